// Round 2
// 545.756 us; speedup vs baseline: 1.0654x; 1.0654x over previous
//
#include <hip/hip_runtime.h>
#include <hip/hip_fp16.h>

// ComposeTransform: out = compose([t1,t2,t3]) with dense displacement fields.
//   r   = t3 + interp(t2, grid + t3)
//   out = r  + interp(t1, grid + r)
// R4 -> R5:
//  - conv(t1) fused into pass-A warp launch as a second block role:
//    warp role uses ~20% HBM / 13% VALU (request-bound scatter), so the
//    BW-bound conversion rides along nearly free. Needs 2 ws buffers
//    (126 MB); falls back to the R4 sequential 4-kernel flow if ws is small.
//  - row-pair gather is an explicit 16B load (global_load_dwordx4) instead
//    of two uint2 loads left to the vectorizer.
//  - nontemporal loads for streaming shift/src reads, nontemporal store for
//    the final (never re-read) output: keep the f16 volume resident in L2.
//  - R5 compile fix: nontemporal builtins need ext_vector_type, not HIP's
//    float2/float4 classes.
// R4 counters: warp 175us @1.6TB/s (20% peak), VALU 13%, occ 82%,
// SQ_LDS_BANK_CONFLICT 0 => scattered-line-request bound; conv ~110us each.

#define BB 2
#define DD 128
#define HH 160
#define WW 192

// warp kernel tiling: block = 256 threads x 2 voxels = 4d x 2h x 64w tile
#define WT_TILES 3   // 192/64
#define HT_TILES 80  // 160/2
#define DT_TILES 32  // 128/4
#define NBLOCKS (WT_TILES * HT_TILES * DT_TILES * BB)  // 15360
#define PER_XCD (NBLOCKS / 8)                          // 1920

#define NVOX ((long)BB * DD * HH * WW)      // 7,864,320 voxels
#define CONV_BLOCKS ((int)(NVOX / 1024))    // 7680
#define VOLH_BYTES ((size_t)NVOX * 8)       // 62,914,560 per f16 volume

typedef unsigned int uint4v __attribute__((ext_vector_type(4)));
typedef uint4v uint4v_a8 __attribute__((aligned(8)));   // 8B-aligned 16B load
typedef float floatx2 __attribute__((ext_vector_type(2)));
typedef float floatx4 __attribute__((ext_vector_type(4)));

static __device__ __forceinline__ float3 cvt_h3(unsigned w0, unsigned w1) {
    float x = __half2float(__ushort_as_half((unsigned short)(w0 & 0xffffu)));
    float y = __half2float(__ushort_as_half((unsigned short)(w0 >> 16)));
    float z = __half2float(__ushort_as_half((unsigned short)(w1 & 0xffffu)));
    return make_float3(x, y, z);
}

// ---------------- conversion role: f32 [.,3] -> f16 padded [.,4] ------------
// Block = 256 threads, 1024 voxels: 768 coalesced float4 loads -> LDS ->
// 4x coalesced uint2 stores per thread.
static __device__ __forceinline__ void conv_body(
    const floatx4* __restrict__ src, uint2* __restrict__ dst, unsigned bid)
{
    __shared__ floatx4 lds4[768];         // 12 KB
    const float* lds = (const float*)lds4;

    long base = (long)bid * 1024;         // first voxel of this block
    const floatx4* s4 = src + (long)bid * 768;
    int tid = threadIdx.x;

#pragma unroll
    for (int j = 0; j < 3; ++j)
        lds4[tid + 256 * j] = __builtin_nontemporal_load(&s4[tid + 256 * j]);
    __syncthreads();

#pragma unroll
    for (int j = 0; j < 4; ++j) {
        int v = tid + 256 * j;
        float x = lds[3 * v], y = lds[3 * v + 1], z = lds[3 * v + 2];
        uint2 q;
        q.x = (unsigned)__half_as_ushort(__float2half_rn(x)) |
              ((unsigned)__half_as_ushort(__float2half_rn(y)) << 16);
        q.y = (unsigned)__half_as_ushort(__float2half_rn(z));
        dst[base + v] = q;
    }
}

__global__ __launch_bounds__(256) void conv_f16_kernel(
    const floatx4* __restrict__ src, uint2* __restrict__ dst)
{
    conv_body(src, dst, blockIdx.x);
}

// ---------------- warp role: out = shift + interp(vol, grid + shift) --------
static __device__ __forceinline__ void interp_one(
    const uint2* __restrict__ baseq, int d, int h, int w,
    float sx, float sy, float sz, float& ox, float& oy, float& oz)
{
    float lx = fminf(fmaxf((float)d + sx, 0.f), (float)(DD - 1));
    float ly = fminf(fmaxf((float)h + sy, 0.f), (float)(HH - 1));
    float lz = fminf(fmaxf((float)w + sz, 0.f), (float)(WW - 1));

    float fx = floorf(lx), fy = floorf(ly), fz = floorf(lz);
    int x0 = (int)fx, y0 = (int)fy, z0 = (int)fz;
    int x1 = min(x0 + 1, DD - 1);
    int y1 = min(y0 + 1, HH - 1);

    int  z0m = min(z0, WW - 2);
    bool zhi = (z0 == WW - 1);

    float wx0 = (float)x1 - lx;
    float wy0 = (float)y1 - ly;
    float wz0 = (float)(min(z0 + 1, WW - 1)) - lz;
    float wx1 = 1.f - wx0;
    float wy1 = 1.f - wy0;
    float wz1 = 1.f - wz0;

    // issue all 4 row-pair 16B loads (independent) before use
    const uint4v_a8* p00 = (const uint4v_a8*)(baseq + (((long)x0 * HH + y0) * WW + z0m));
    const uint4v_a8* p01 = (const uint4v_a8*)(baseq + (((long)x0 * HH + y1) * WW + z0m));
    const uint4v_a8* p10 = (const uint4v_a8*)(baseq + (((long)x1 * HH + y0) * WW + z0m));
    const uint4v_a8* p11 = (const uint4v_a8*)(baseq + (((long)x1 * HH + y1) * WW + z0m));
    uint4v q00 = *p00;
    uint4v q01 = *p01;
    uint4v q10 = *p10;
    uint4v q11 = *p11;

    float ax = 0.f, ay = 0.f, az = 0.f;
#define ROWPAIR(Q, WXY) do {                                                \
        float3 vlo = cvt_h3(Q.x, Q.y);                                      \
        float3 vhi = cvt_h3(Q.z, Q.w);                                      \
        float3 v0  = zhi ? vhi : vlo;                                       \
        float wt_ = (WXY);                                                  \
        ax = fmaf(wt_, fmaf(wz0, v0.x, wz1 * vhi.x), ax);                   \
        ay = fmaf(wt_, fmaf(wz0, v0.y, wz1 * vhi.y), ay);                   \
        az = fmaf(wt_, fmaf(wz0, v0.z, wz1 * vhi.z), az);                   \
    } while (0)
    ROWPAIR(q00, wx0 * wy0);
    ROWPAIR(q01, wx0 * wy1);
    ROWPAIR(q10, wx1 * wy0);
    ROWPAIR(q11, wx1 * wy1);
#undef ROWPAIR

    ox = sx + ax;
    oy = sy + ay;
    oz = sz + az;
}

template <bool NTSTORE>
static __device__ __forceinline__ void warp_body(
    const uint2* __restrict__ vol4,  // sampled field, f16 padded [B,D,H,W,4]
    const float* shift,              // current transform (may alias out)
    float* out, unsigned bid)
{
    // XCD swizzle: contiguous spatial slab per XCD for L2 halo reuse.
    unsigned sbid = (bid & 7u) * PER_XCD + (bid >> 3);

    unsigned wt  = sbid % WT_TILES;  unsigned t0 = sbid / WT_TILES;
    unsigned ht  = t0 % HT_TILES;    unsigned t1 = t0 / HT_TILES;
    unsigned dt  = t1 % DT_TILES;    unsigned b  = t1 / DT_TILES;

    unsigned tid = threadIdx.x;
    int w = wt * 64 + 2 * (tid & 31);        // even; handles w, w+1
    int h = ht * 2  + ((tid >> 5) & 1);
    int d = dt * 4  + (tid >> 6);

    const long nvb = (long)DD * HH * WW;
    long idx = (long)b * nvb + (((long)d * HH + h) * WW + w);

    // 2 voxels' shifts: 6 contiguous floats, 8B-aligned, streamed once
    const floatx2* sp2 = (const floatx2*)(shift + idx * 3);
    floatx2 sa = __builtin_nontemporal_load(&sp2[0]);
    floatx2 sb = __builtin_nontemporal_load(&sp2[1]);
    floatx2 sc = __builtin_nontemporal_load(&sp2[2]);

    const uint2* baseq = vol4 + (long)b * nvb;

    float o0x, o0y, o0z, o1x, o1y, o1z;
    interp_one(baseq, d, h, w,     sa.x, sa.y, sb.x, o0x, o0y, o0z);
    interp_one(baseq, d, h, w + 1, sb.y, sc.x, sc.y, o1x, o1y, o1z);

    floatx2* op2 = (floatx2*)(out + idx * 3);
    floatx2 r0; r0.x = o0x; r0.y = o0y;
    floatx2 r1; r1.x = o0z; r1.y = o1x;
    floatx2 r2; r2.x = o1y; r2.y = o1z;
    if (NTSTORE) {
        __builtin_nontemporal_store(r0, &op2[0]);
        __builtin_nontemporal_store(r1, &op2[1]);
        __builtin_nontemporal_store(r2, &op2[2]);
    } else {
        op2[0] = r0;
        op2[1] = r1;
        op2[2] = r2;
    }
}

__global__ __launch_bounds__(256) void warp_add_h_kernel(
    const uint2* __restrict__ vol4, const float* shift, float* out)
{
    warp_body<false>(vol4, shift, out, blockIdx.x);
}

__global__ __launch_bounds__(256) void warp_add_h_nt_kernel(
    const uint2* __restrict__ vol4, const float* shift, float* out)
{
    warp_body<true>(vol4, shift, out, blockIdx.x);
}

// Pass A warp + conv(t1) overlapped: first CONV_BLOCKS blocks convert t1
// into volB (pure BW), the rest run the request-bound warp of volA.
// CONV_BLOCKS = 7680 is a multiple of 8, so the warp role's XCD swizzle
// (bid & 7) keeps the same XCD alignment as a standalone launch.
__global__ __launch_bounds__(256) void fused_warp_conv_kernel(
    const uint2* __restrict__ vol4, const float* shift, float* out,
    const floatx4* __restrict__ csrc, uint2* __restrict__ cdst)
{
    unsigned bid = blockIdx.x;
    if (bid < (unsigned)CONV_BLOCKS) {
        conv_body(csrc, cdst, bid);
    } else {
        warp_body<false>(vol4, shift, out, bid - CONV_BLOCKS);
    }
}

extern "C" void kernel_launch(void* const* d_in, const int* in_sizes, int n_in,
                              void* d_out, int out_size, void* d_ws, size_t ws_size,
                              hipStream_t stream) {
    const float* t1 = (const float*)d_in[0];
    const float* t2 = (const float*)d_in[1];
    const float* t3 = (const float*)d_in[2];
    float* out  = (float*)d_out;

    uint2* volA = (uint2*)d_ws;

    if (ws_size >= 2 * VOLH_BYTES) {
        uint2* volB = (uint2*)((char*)d_ws + VOLH_BYTES);
        // K1: stage t2 as f16
        conv_f16_kernel<<<CONV_BLOCKS, 256, 0, stream>>>((const floatx4*)t2, volA);
        // K2: r = t3 + interp(t2, grid+t3) -> out, overlapped with conv(t1)->volB
        fused_warp_conv_kernel<<<CONV_BLOCKS + NBLOCKS, 256, 0, stream>>>(
            volA, t3, out, (const floatx4*)t1, volB);
        // K3: out = r + interp(t1, grid+r), in-place, final write never re-read
        warp_add_h_nt_kernel<<<NBLOCKS, 256, 0, stream>>>(volB, out, out);
    } else {
        // Fallback: R4 sequential flow with a single staged volume.
        conv_f16_kernel<<<CONV_BLOCKS, 256, 0, stream>>>((const floatx4*)t2, volA);
        warp_add_h_kernel<<<NBLOCKS, 256, 0, stream>>>(volA, t3, out);
        conv_f16_kernel<<<CONV_BLOCKS, 256, 0, stream>>>((const floatx4*)t1, volA);
        warp_add_h_nt_kernel<<<NBLOCKS, 256, 0, stream>>>(volA, out, out);
    }
}